// Round 1
// baseline (86.167 us; speedup 1.0000x reference)
//
#include <hip/hip_runtime.h>
#include <hip/hip_bf16.h>

#define BATCH 128
#define NOUT  256
#define MB    8
#define IN    512

#define TI 16
#define TB 16
#define THREADS 256
#define CH 256            // k-chunk in floats
#define CH4 (CH/4)        // 64 float4 per row-chunk
#define STRIDE4 65        // float4 LDS row stride (260 floats: (260%32)=4 -> only 2-way bank aliasing, free)

__device__ __forceinline__ float fast_exp2(float x) {
#if __has_builtin(__builtin_amdgcn_exp2f)
  return __builtin_amdgcn_exp2f(x);
#else
  return exp2f(x);
#endif
}
__device__ __forceinline__ float fast_rcp(float x) {
#if __has_builtin(__builtin_amdgcn_rcpf)
  return __builtin_amdgcn_rcpf(x);
#else
  return 1.0f / x;
#endif
}

// Kernel A: partial[z][i][b] = prod over this block's j-range of sum_k sigmoid(x[i,j,k]*w[b,j,k])
__global__ __launch_bounds__(THREADS) void dnm_partial_kernel(
    const float* __restrict__ x, const float* __restrict__ w,
    float* __restrict__ part, int j_per_block)
{
  __shared__ float4 xs4[TI * STRIDE4];
  __shared__ float4 ws4[TB * STRIDE4];

  const int t  = threadIdx.x;
  const int ti = t >> 4;      // 0..15  (i within tile)
  const int tb = t & 15;      // 0..15  (b within tile)
  const int b0 = blockIdx.x * TB;
  const int i0 = blockIdx.y * TI;
  const int j0 = blockIdx.z * j_per_block;

  const float4* gx = (const float4*)x;
  const float4* gw = (const float4*)w;
  const float NEG_LOG2E = -1.4426950408889634f;

  float prod = 1.0f;
  for (int j = j0; j < j0 + j_per_block; ++j) {
    float acc0 = 0.0f, acc1 = 0.0f;
    for (int kc = 0; kc < IN / CH; ++kc) {
      __syncthreads();  // previous chunk's LDS reads done before restaging
      // stage x tile (scaled by -log2e) and w tile: 16 rows x 64 float4 each
      #pragma unroll
      for (int p = 0; p < (TI * CH4) / THREADS; ++p) {
        int idx = t + p * THREADS;
        int r = idx >> 6, c4 = idx & 63;
        float4 xv = gx[(size_t)((i0 + r) * MB + j) * (IN / 4) + kc * CH4 + c4];
        xv.x *= NEG_LOG2E; xv.y *= NEG_LOG2E; xv.z *= NEG_LOG2E; xv.w *= NEG_LOG2E;
        xs4[r * STRIDE4 + c4] = xv;
        ws4[r * STRIDE4 + c4] = gw[(size_t)((b0 + r) * MB + j) * (IN / 4) + kc * CH4 + c4];
      }
      __syncthreads();
      const float4* __restrict__ xr = &xs4[ti * STRIDE4];
      const float4* __restrict__ wr = &ws4[tb * STRIDE4];
      #pragma unroll 8
      for (int k4 = 0; k4 < CH4; ++k4) {
        float4 xv = xr[k4];
        float4 wv = wr[k4];
        // a = exp(-x*w) via exp2 of pre-scaled x
        float a = fast_exp2(xv.x * wv.x);
        float b = fast_exp2(xv.y * wv.y);
        float c = fast_exp2(xv.z * wv.z);
        float d = fast_exp2(xv.w * wv.w);
        // sigma(v0)+sigma(v1) = (2+a+b)/(1+a+b+ab): one rcp per 2 elements
        float u0 = (a + b) + 1.0f;
        float d0 = fmaf(a, b, u0);
        float n0 = u0 + 1.0f;
        acc0 = fmaf(n0, fast_rcp(d0), acc0);
        float u1 = (c + d) + 1.0f;
        float d1 = fmaf(c, d, u1);
        float n1 = u1 + 1.0f;
        acc1 = fmaf(n1, fast_rcp(d1), acc1);
      }
    }
    prod *= (acc0 + acc1);
  }
  part[(size_t)blockIdx.z * (BATCH * NOUT) + (size_t)(i0 + ti) * NOUT + (b0 + tb)] = prod;
}

__device__ __forceinline__ float block_sum(float v, float* red) {
  #pragma unroll
  for (int o = 32; o > 0; o >>= 1) v += __shfl_down(v, o, 64);
  int lane = threadIdx.x & 63, wid = threadIdx.x >> 6;
  __syncthreads();  // protect red[] reuse across calls
  if (lane == 0) red[wid] = v;
  __syncthreads();
  return red[0] + red[1] + red[2] + red[3];
}

// Kernel B: combine jg partial products, then per-row normalize (sum->1) and standardize (ddof=1)
__global__ __launch_bounds__(256) void dnm_norm_kernel(
    const float* __restrict__ part, float* __restrict__ out, int jg)
{
  __shared__ float red[4];
  const int i = blockIdx.x;
  const int t = threadIdx.x;
  float z = 1.0f;
  for (int g = 0; g < jg; ++g)
    z *= part[(size_t)g * (BATCH * NOUT) + (size_t)i * NOUT + t];

  float S  = block_sum(z, red);
  float zn = z / S;
  float m  = block_sum(zn, red) * (1.0f / NOUT);
  float dv = zn - m;
  float v  = block_sum(dv * dv, red) * (1.0f / (NOUT - 1));
  out[(size_t)i * NOUT + t] = dv / sqrtf(v);
}

extern "C" void kernel_launch(void* const* d_in, const int* in_sizes, int n_in,
                              void* d_out, int out_size, void* d_ws, size_t ws_size,
                              hipStream_t stream) {
  const float* x = (const float*)d_in[0];   // (128, 8, 512)
  const float* w = (const float*)d_in[1];   // (256, 8, 512)
  float* out = (float*)d_out;               // (128, 256)

  const size_t plane = (size_t)BATCH * NOUT * sizeof(float);
  int jg;
  float* part;
  if (ws_size >= 4 * plane)      { jg = 4; part = (float*)d_ws; }
  else if (ws_size >= 2 * plane) { jg = 2; part = (float*)d_ws; }
  else if (ws_size >= plane)     { jg = 1; part = (float*)d_ws; }
  else                           { jg = 1; part = out; }  // in-place fallback (safe: reads precede writes across barriers)

  const int jpb = MB / jg;
  dim3 gridA(NOUT / TB, BATCH / TI, jg);
  dnm_partial_kernel<<<gridA, THREADS, 0, stream>>>(x, w, part, jpb);
  dnm_norm_kernel<<<dim3(BATCH), 256, 0, stream>>>(part, out, jg);
}